// Round 9
// baseline (780.682 us; speedup 1.0000x reference)
//
#include <hip/hip_runtime.h>

#define N_TOT 4096
#define HIDN  1024
#define EMBD  256
#define VOC   1024
#define NSTEP 12

typedef __bf16 bf16;
typedef _Float16 h16;
typedef __bf16 bf16x8 __attribute__((ext_vector_type(8)));
typedef __bf16 bf16x4 __attribute__((ext_vector_type(4)));
typedef _Float16 h16x8 __attribute__((ext_vector_type(8)));
typedef float  f32x4  __attribute__((ext_vector_type(4)));

#define VMCNT(n) asm volatile("s_waitcnt vmcnt(" #n ")" ::: "memory")
#define MEMFENCE() asm volatile("" ::: "memory")

static __device__ __forceinline__ f32x4 mfma16(bf16x8 a, bf16x8 b, f32x4 c) {
  return __builtin_amdgcn_mfma_f32_16x16x32_bf16(a, b, c, 0, 0, 0);
}

static __device__ __forceinline__ float fast_tanh(float x) {
  // tanh(x) = 1 - 2/(e^{2x}+1); bf16-accurate, ~6 VALU ops vs libcall ~20+
  float e = __expf(2.0f * x);
  return 1.0f - 2.0f / (e + 1.0f);
}

// async global->LDS, 16B per lane. LDS dest is wave-uniform base + lane*16;
// global source is per-lane (pre-swizzled to realize the XOR-swizzled layout).
static __device__ __forceinline__ void gload16(const bf16* g, bf16* l) {
  __builtin_amdgcn_global_load_lds(
      (const __attribute__((address_space(1))) void*)g,
      (__attribute__((address_space(3))) void*)l, 16, 0, 0);
}

// ---------------- fused prep kernel ----------------

__global__ void prep_kernel(const float* __restrict__ Wih, const float* __restrict__ Whh,
                            const float* __restrict__ Wout, const float* __restrict__ Wemb,
                            const float* __restrict__ target, const float* __restrict__ sos,
                            const float* __restrict__ bih, const float* __restrict__ bhh,
                            bf16* __restrict__ wih_b, bf16* __restrict__ whh_b,
                            bf16* __restrict__ wout_b, bf16* __restrict__ wemb_b,
                            bf16* __restrict__ hbuf, bf16* __restrict__ ebuf,
                            float* __restrict__ bias1) {
  for (int q = blockIdx.x * blockDim.x + threadIdx.x; q < 1966336;
       q += blockDim.x * gridDim.x) {
    if (q < 1703936) {
      const float* s; bf16* d; int o;
      if (q < 65536)        { s = Wih;    d = wih_b;  o = q; }
      else if (q < 327680)  { s = Whh;    d = whh_b;  o = q - 65536; }
      else if (q < 589824)  { s = Wout;   d = wout_b; o = q - 327680; }
      else if (q < 655360)  { s = Wemb;   d = wemb_b; o = q - 589824; }
      else                  { s = target; d = hbuf;   o = q - 655360; }
      f32x4 v = *(const f32x4*)&s[(size_t)o * 4];
      bf16x4 b; b[0] = (bf16)v.x; b[1] = (bf16)v.y; b[2] = (bf16)v.z; b[3] = (bf16)v.w;
      *(bf16x4*)&d[(size_t)o * 4] = b;
    } else if (q < 1966080) {
      int o = q - 1703936;
      f32x4 v = *(const f32x4*)&sos[(o & 63) * 4];
      bf16x4 b; b[0] = (bf16)v.x; b[1] = (bf16)v.y; b[2] = (bf16)v.z; b[3] = (bf16)v.w;
      *(bf16x4*)&ebuf[(size_t)o * 4] = b;
    } else {
      int o = q - 1966080;
      f32x4 a = *(const f32x4*)&bih[o * 4];
      f32x4 c = *(const f32x4*)&bhh[o * 4];
      f32x4 r; r.x = a.x + c.x; r.y = a.y + c.y; r.z = a.z + c.z; r.w = a.w + c.w;
      *(f32x4*)&bias1[o * 4] = r;
    }
  }
}

// ===== GEMM core: 128x64 block tile, 2 waves, each wave 64x64 (4x4 frags) =====
// reads/MFMA = 0.5 (balanced vs MFMA pipe). BK=64. LDS: 2 buffers x (A 16KB + B 8KB)
// = 48 KB -> 2-3 blocks/CU. 2-phase: stage(t+1); compute(t); vmcnt(0); barrier.

template <bool TWO, int NT>
static __device__ __forceinline__ void pipe_gemm(
    const bf16* __restrict__ A0, const bf16* __restrict__ B0, int K0,
    const bf16* __restrict__ A1, const bf16* __restrict__ B1, int K1,
    bf16* lds, int m0, int n0, int w, int lane, f32x4 acc[4][4])
{
  const int lr = lane & 15, lk = lane >> 4;
  const int srow = lane >> 3;
  const int scol = (((lane & 7) ^ srow) << 3);

  auto stage = [&](int t, int bsel) {
    const bf16 *A, *B; int K, k0;
    if (TWO && t < 4) { A = A0; B = B0; K = K0; k0 = t << 6; }
    else if (TWO)     { A = A1; B = B1; K = K1; k0 = (t - 4) << 6; }
    else              { A = A0; B = B0; K = K0; k0 = t << 6; }
    bf16* base = lds + bsel * 12288;
#pragma unroll
    for (int r = 0; r < 8; ++r)                      // A: wave stages 64 rows
      gload16(&A[(size_t)(m0 + w * 64 + r * 8 + srow) * K + k0 + scol],
              base + (w * 64 + r * 8) * 64);
#pragma unroll
    for (int r = 0; r < 4; ++r)                      // B: wave stages 32 rows
      gload16(&B[(size_t)(n0 + w * 32 + r * 8 + srow) * K + k0 + scol],
              base + 8192 + (w * 32 + r * 8) * 64);
  };

  stage(0, 0);
  VMCNT(0);
  MEMFENCE();
  __builtin_amdgcn_s_barrier();
  MEMFENCE();
  for (int t = 0; t < NT; ++t) {
    if (t + 1 < NT) stage(t + 1, (t + 1) & 1);
    const bf16* Ab = lds + (t & 1) * 12288;
    const bf16* Bb = Ab + 8192;
#pragma unroll
    for (int kk = 0; kk < 2; ++kk) {
      bf16x8 af[4], bf[4];
#pragma unroll
      for (int mi = 0; mi < 4; ++mi) {
        int row = w * 64 + mi * 16 + lr;
        af[mi] = *(const bf16x8*)&Ab[row * 64 + ((((kk << 2) | lk) ^ (row & 7)) << 3)];
      }
#pragma unroll
      for (int ni = 0; ni < 4; ++ni) {
        int row = ni * 16 + lr;
        bf[ni] = *(const bf16x8*)&Bb[row * 64 + ((((kk << 2) | lk) ^ (row & 7)) << 3)];
      }
#pragma unroll
      for (int mi = 0; mi < 4; ++mi)
#pragma unroll
        for (int ni = 0; ni < 4; ++ni)
          acc[mi][ni] = mfma16(af[mi], bf[ni], acc[mi][ni]);
    }
    if (t + 1 < NT) {
      VMCNT(0);                       // tile t+1 landed; hidden by the 32 MFMAs above
      MEMFENCE();
      __builtin_amdgcn_s_barrier();
      MEMFENCE();
    }
  }
}

// ---------------- k1: RNN cell ----------------

__global__ __launch_bounds__(128)
void rnn_cell_kernel(const bf16* __restrict__ e,     // [N][EMBD]
                     const bf16* __restrict__ hprev, // [N][HIDN]
                     const bf16* __restrict__ Wih,   // [HIDN][EMBD]
                     const bf16* __restrict__ Whh,   // [HIDN][HIDN]
                     const float* __restrict__ bias, // [HIDN]
                     bf16* __restrict__ hnew)        // [N][HIDN]
{
  __shared__ bf16 lds[2 * 12288];    // 48 KB
  const int tid = threadIdx.x;
  const int lane = tid & 63;
  const int w = tid >> 6;            // 0..1
  const int id = (blockIdx.x & 7) * 64 + (blockIdx.x >> 3);  // 512 blocks, bijective
  const int m0 = (id >> 4) * 128;    // 32 m-tiles
  const int n0 = (id & 15) * 64;     // 16 n-tiles
  const int lr = lane & 15, lk = lane >> 4;

  f32x4 acc[4][4] = {};
  pipe_gemm<true, 20>(e, Wih, EMBD, hprev, Whh, HIDN, lds, m0, n0, w, lane, acc);

#pragma unroll
  for (int mi = 0; mi < 4; ++mi) {
    int rowb = m0 + w * 64 + mi * 16 + lk * 4;
#pragma unroll
    for (int ni = 0; ni < 4; ++ni) {
      int col = n0 + ni * 16 + lr;
      float bs = bias[col];
#pragma unroll
      for (int j = 0; j < 4; ++j)
        hnew[(size_t)(rowb + j) * HIDN + col] = (bf16)fast_tanh(acc[mi][ni][j] + bs);
    }
  }
}

// ---------------- k2: logits = h@Wout^T + b_out -> fp16 scratch ----------------

__global__ __launch_bounds__(128)
void logits_kernel(const bf16* __restrict__ h,    // [N][HIDN]
                   const bf16* __restrict__ Wout, // [VOC][HIDN]
                   const float* __restrict__ bout,
                   h16* __restrict__ lbuf)        // [N][VOC]
{
  __shared__ bf16 lds[2 * 12288];
  const int tid = threadIdx.x;
  const int lane = tid & 63;
  const int w = tid >> 6;
  const int id = (blockIdx.x & 7) * 64 + (blockIdx.x >> 3);
  const int m0 = (id >> 4) * 128;
  const int n0 = (id & 15) * 64;
  const int lr = lane & 15, lk = lane >> 4;

  f32x4 acc[4][4] = {};
  pipe_gemm<false, 16>(h, Wout, HIDN, nullptr, nullptr, 0, lds, m0, n0, w, lane, acc);

#pragma unroll
  for (int mi = 0; mi < 4; ++mi) {
    int rowb = m0 + w * 64 + mi * 16 + lk * 4;
#pragma unroll
    for (int ni = 0; ni < 4; ++ni) {
      int col = n0 + ni * 16 + lr;
      float bs = bout[col];
#pragma unroll
      for (int j = 0; j < 4; ++j) {
        int row = rowb + j;
        lbuf[(size_t)row * VOC + col] = (h16)(acc[mi][ni][j] + bs);
      }
    }
  }
}

// ---------------- k3: softmax((l+g)) -> fp32 d_out + e_next = x@Wemb^T + b_emb ----------

__global__ __launch_bounds__(512)
void softmax_emb_kernel(const h16* __restrict__ lbuf,  // [N][VOC]
                        const float* __restrict__ gum, // [N][VOC] (step slice)
                        const bf16* __restrict__ Wemb, // [EMBD][VOC]
                        const float* __restrict__ bemb,
                        float* __restrict__ out,       // [N][NSTEP][VOC]
                        bf16* __restrict__ enext,      // [N][EMBD]
                        int step)
{
  __shared__ bf16 xs[16 * 1032];
  const int tid = threadIdx.x;
  const int lane = tid & 63;
  const int w = tid >> 6;       // 0..7
  const int n0 = blockIdx.x * 16;

  for (int rr = 0; rr < 2; ++rr) {
    int r = w + rr * 8;
    const h16* lrow = lbuf + (size_t)(n0 + r) * VOC;
    const float* grow = gum + (size_t)(n0 + r) * VOC;
    float s[16];
    float m = -1e30f;
#pragma unroll
    for (int i = 0; i < 2; ++i) {
      h16x8 lv = *(const h16x8*)&lrow[i * 512 + lane * 8];
      f32x4 g0 = *(const f32x4*)&grow[i * 512 + lane * 8];
      f32x4 g1 = *(const f32x4*)&grow[i * 512 + lane * 8 + 4];
#pragma unroll
      for (int j = 0; j < 4; ++j) {
        float f0 = (float)lv[j] + g0[j];
        float f1 = (float)lv[4 + j] + g1[j];
        s[i * 8 + j] = f0; s[i * 8 + 4 + j] = f1;
        m = fmaxf(m, fmaxf(f0, f1));
      }
    }
#pragma unroll
    for (int off = 32; off; off >>= 1) m = fmaxf(m, __shfl_xor(m, off));
    float sum = 0.f;
#pragma unroll
    for (int i = 0; i < 16; ++i) { s[i] = __expf(s[i] - m); sum += s[i]; }
#pragma unroll
    for (int off = 32; off; off >>= 1) sum += __shfl_xor(sum, off);
    float inv = 1.0f / sum;
    float* orow = out + ((size_t)(n0 + r) * NSTEP + step) * VOC;
#pragma unroll
    for (int i = 0; i < 2; ++i) {
      f32x4 v0, v1;
      bf16x8 bv;
#pragma unroll
      for (int j = 0; j < 4; ++j) {
        float x0 = s[i * 8 + j] * inv;
        float x1 = s[i * 8 + 4 + j] * inv;
        v0[j] = x0; v1[j] = x1;
        bv[j] = (bf16)x0; bv[4 + j] = (bf16)x1;
      }
      *(f32x4*)&orow[i * 512 + lane * 8] = v0;
      *(f32x4*)&orow[i * 512 + lane * 8 + 4] = v1;
      *(bf16x8*)&xs[r * 1032 + i * 512 + lane * 8] = bv;
    }
  }
  __syncthreads();

  const int lr = lane & 15, lk = lane >> 4;
  f32x4 acc[2] = {};
  for (int k0 = 0; k0 < VOC; k0 += 32) {
    bf16x8 a = *(bf16x8*)&xs[lr * 1032 + k0 + lk * 8];
#pragma unroll
    for (int ni = 0; ni < 2; ++ni) {
      int col = w * 32 + ni * 16 + lr;
      bf16x8 b = *(const bf16x8*)&Wemb[(size_t)col * VOC + k0 + lk * 8];
      acc[ni] = mfma16(a, b, acc[ni]);
    }
  }
#pragma unroll
  for (int ni = 0; ni < 2; ++ni) {
    int col = w * 32 + ni * 16 + lr;
    float bb = bemb[col];
#pragma unroll
    for (int j = 0; j < 4; ++j) {
      int n = n0 + lk * 4 + j;
      enext[(size_t)n * EMBD + col] = (bf16)(acc[ni][j] + bb);
    }
  }
}

// ---------------- launch ----------------

extern "C" void kernel_launch(void* const* d_in, const int* in_sizes, int n_in,
                              void* d_out, int out_size, void* d_ws, size_t ws_size,
                              hipStream_t stream) {
  const float* target  = (const float*)d_in[0];
  const float* gumbels = (const float*)d_in[1];
  const float* sos     = (const float*)d_in[2];
  const float* W_ih    = (const float*)d_in[3];
  const float* b_ih    = (const float*)d_in[4];
  const float* W_hh    = (const float*)d_in[5];
  const float* b_hh    = (const float*)d_in[6];
  const float* W_out   = (const float*)d_in[7];
  const float* b_out   = (const float*)d_in[8];
  const float* W_emb   = (const float*)d_in[9];
  const float* b_emb   = (const float*)d_in[10];
  float* out = (float*)d_out;

  char* ws = (char*)d_ws;
  bf16* wih_b  = (bf16*)(ws);                // 512 KB
  bf16* whh_b  = (bf16*)(ws + (1u << 20));   // 2 MB
  bf16* wout_b = (bf16*)(ws + (3u << 20));   // 2 MB
  bf16* wemb_b = (bf16*)(ws + (5u << 20));   // 512 KB
  float* bias1 = (float*)(ws + (6u << 20));  // 4 KB
  bf16* hbuf0  = (bf16*)(ws + (7u << 20));   // 8 MB
  bf16* hbuf1  = (bf16*)(ws + (15u << 20));  // 8 MB
  bf16* ebuf   = (bf16*)(ws + (23u << 20));  // 2 MB
  h16*  lbuf   = (h16*) (ws + (25u << 20));  // 8 MB

  prep_kernel<<<2048, 256, 0, stream>>>(W_ih, W_hh, W_out, W_emb, target, sos,
                                        b_ih, b_hh, wih_b, whh_b, wout_b, wemb_b,
                                        hbuf0, ebuf, bias1);

  bf16* hb[2] = {hbuf0, hbuf1};
  for (int t = 0; t < NSTEP; ++t) {
    bf16* hp = hb[t & 1];
    bf16* hn = hb[(t + 1) & 1];
    rnn_cell_kernel<<<(N_TOT / 128) * (HIDN / 64), 128, 0, stream>>>(
        ebuf, hp, wih_b, whh_b, bias1, hn);
    logits_kernel<<<(N_TOT / 128) * (VOC / 64), 128, 0, stream>>>(
        hn, wout_b, b_out, lbuf);
    softmax_emb_kernel<<<N_TOT / 16, 512, 0, stream>>>(
        lbuf, gumbels + (size_t)t * N_TOT * VOC, wemb_b, b_emb, out, ebuf, t);
  }
}

// Round 10
// 648.987 us; speedup vs baseline: 1.2029x; 1.2029x over previous
//
#include <hip/hip_runtime.h>

#define N_TOT 4096
#define HIDN  1024
#define EMBD  256
#define VOC   1024
#define NSTEP 12

typedef __bf16 bf16;
typedef _Float16 h16;
typedef __bf16 bf16x8 __attribute__((ext_vector_type(8)));
typedef __bf16 bf16x4 __attribute__((ext_vector_type(4)));
typedef _Float16 h16x8 __attribute__((ext_vector_type(8)));
typedef float  f32x4  __attribute__((ext_vector_type(4)));

#define VMCNT(n) asm volatile("s_waitcnt vmcnt(" #n ")" ::: "memory")
#define MEMFENCE() asm volatile("" ::: "memory")

static __device__ __forceinline__ f32x4 mfma16(bf16x8 a, bf16x8 b, f32x4 c) {
  return __builtin_amdgcn_mfma_f32_16x16x32_bf16(a, b, c, 0, 0, 0);
}

static __device__ __forceinline__ float fast_tanh(float x) {
  float e = __expf(2.0f * x);
  return 1.0f - 2.0f / (e + 1.0f);
}

// async global->LDS, 16B per lane. LDS dest is wave-uniform base + lane*16;
// global source is per-lane (pre-swizzled to realize the XOR-swizzled layout).
static __device__ __forceinline__ void gload16(const bf16* g, bf16* l) {
  __builtin_amdgcn_global_load_lds(
      (const __attribute__((address_space(1))) void*)g,
      (__attribute__((address_space(3))) void*)l, 16, 0, 0);
}

// ---------------- fused prep kernel ----------------

__global__ void prep_kernel(const float* __restrict__ Wih, const float* __restrict__ Whh,
                            const float* __restrict__ Wout, const float* __restrict__ Wemb,
                            const float* __restrict__ target, const float* __restrict__ sos,
                            const float* __restrict__ bih, const float* __restrict__ bhh,
                            bf16* __restrict__ wih_b, bf16* __restrict__ whh_b,
                            bf16* __restrict__ wout_b, bf16* __restrict__ wemb_b,
                            bf16* __restrict__ hbuf, bf16* __restrict__ ebuf,
                            float* __restrict__ bias1) {
  for (int q = blockIdx.x * blockDim.x + threadIdx.x; q < 1966336;
       q += blockDim.x * gridDim.x) {
    if (q < 1703936) {
      const float* s; bf16* d; int o;
      if (q < 65536)        { s = Wih;    d = wih_b;  o = q; }
      else if (q < 327680)  { s = Whh;    d = whh_b;  o = q - 65536; }
      else if (q < 589824)  { s = Wout;   d = wout_b; o = q - 327680; }
      else if (q < 655360)  { s = Wemb;   d = wemb_b; o = q - 589824; }
      else                  { s = target; d = hbuf;   o = q - 655360; }
      f32x4 v = *(const f32x4*)&s[(size_t)o * 4];
      bf16x4 b; b[0] = (bf16)v.x; b[1] = (bf16)v.y; b[2] = (bf16)v.z; b[3] = (bf16)v.w;
      *(bf16x4*)&d[(size_t)o * 4] = b;
    } else if (q < 1966080) {
      int o = q - 1703936;
      f32x4 v = *(const f32x4*)&sos[(o & 63) * 4];
      bf16x4 b; b[0] = (bf16)v.x; b[1] = (bf16)v.y; b[2] = (bf16)v.z; b[3] = (bf16)v.w;
      *(bf16x4*)&ebuf[(size_t)o * 4] = b;
    } else {
      int o = q - 1966080;
      f32x4 a = *(const f32x4*)&bih[o * 4];
      f32x4 c = *(const f32x4*)&bhh[o * 4];
      f32x4 r; r.x = a.x + c.x; r.y = a.y + c.y; r.z = a.z + c.z; r.w = a.w + c.w;
      *(f32x4*)&bias1[o * 4] = r;
    }
  }
}

// ===== GEMM core (r8 config): 128x64 tile, 4 waves (2x2), BK=64, 3-deep pipeline =====
// LDS: 3 x 24KB = 72KB -> 2 blocks/CU. Per iter t: stage(t+2); MFMA(t) [setprio];
// vmcnt(6) [tile t+1 landed, hidden under MFMAs]; barrier.

template <bool TWO, int NT>
static __device__ __forceinline__ void pipe_gemm(
    const bf16* __restrict__ A0, const bf16* __restrict__ B0, int K0,
    const bf16* __restrict__ A1, const bf16* __restrict__ B1, int K1,
    bf16* lds, int m0, int n0, int w, int lane, f32x4 acc[4][2])
{
  const int wr = w >> 1, wc = w & 1;
  const int lr = lane & 15, lk = lane >> 4;
  const int srow = lane >> 3;
  const int scol = (((lane & 7) ^ srow) << 3);

  auto stage = [&](int t, int bsel) {
    const bf16 *A, *B; int K, k0;
    if (TWO && t < 4) { A = A0; B = B0; K = K0; k0 = t << 6; }
    else if (TWO)     { A = A1; B = B1; K = K1; k0 = (t - 4) << 6; }
    else              { A = A0; B = B0; K = K0; k0 = t << 6; }
    bf16* base = lds + bsel * 12288;
#pragma unroll
    for (int r = 0; r < 4; ++r)
      gload16(&A[(size_t)(m0 + w * 32 + r * 8 + srow) * K + k0 + scol],
              base + (w * 32 + r * 8) * 64);
#pragma unroll
    for (int r = 0; r < 2; ++r)
      gload16(&B[(size_t)(n0 + w * 16 + r * 8 + srow) * K + k0 + scol],
              base + 8192 + (w * 16 + r * 8) * 64);
  };

  stage(0, 0); stage(1, 1);
  VMCNT(6);
  MEMFENCE();
  __builtin_amdgcn_s_barrier();
  MEMFENCE();
  for (int t = 0; t < NT; ++t) {
    if (t + 2 < NT) stage(t + 2, (t + 2) % 3);
    const bf16* Ab = lds + (t % 3) * 12288;
    const bf16* Bb = Ab + 8192;
    __builtin_amdgcn_s_setprio(1);
#pragma unroll
    for (int kk = 0; kk < 2; ++kk) {
      bf16x8 af[4], bfr[2];
#pragma unroll
      for (int mi = 0; mi < 4; ++mi) {
        int row = wr * 64 + mi * 16 + lr;
        af[mi] = *(const bf16x8*)&Ab[row * 64 + ((((kk << 2) | lk) ^ (row & 7)) << 3)];
      }
#pragma unroll
      for (int ni = 0; ni < 2; ++ni) {
        int row = wc * 32 + ni * 16 + lr;
        bfr[ni] = *(const bf16x8*)&Bb[row * 64 + ((((kk << 2) | lk) ^ (row & 7)) << 3)];
      }
#pragma unroll
      for (int mi = 0; mi < 4; ++mi)
#pragma unroll
        for (int ni = 0; ni < 2; ++ni)
          acc[mi][ni] = mfma16(af[mi], bfr[ni], acc[mi][ni]);
    }
    __builtin_amdgcn_s_setprio(0);
    if (t < NT - 2)       VMCNT(6);
    else if (t == NT - 2) VMCNT(0);
    MEMFENCE();
    __builtin_amdgcn_s_barrier();
    MEMFENCE();
  }
}

// ---------------- k1: RNN cell ----------------

__global__ __launch_bounds__(256, 2)
void rnn_cell_kernel(const bf16* __restrict__ e,     // [N][EMBD]
                     const bf16* __restrict__ hprev, // [N][HIDN]
                     const bf16* __restrict__ Wih,   // [HIDN][EMBD]
                     const bf16* __restrict__ Whh,   // [HIDN][HIDN]
                     const float* __restrict__ bias, // [HIDN]
                     bf16* __restrict__ hnew)        // [N][HIDN]
{
  __shared__ bf16 lds[3 * 12288];    // 72 KB
  const int tid = threadIdx.x;
  const int lane = tid & 63;
  const int w = tid >> 6;
  const int wr = w >> 1, wc = w & 1;
  const int id = (blockIdx.x & 7) * 64 + (blockIdx.x >> 3);  // 512 blocks, bijective
  const int m0 = (id >> 4) * 128;
  const int n0 = (id & 15) * 64;
  const int lr = lane & 15, lk = lane >> 4;

  f32x4 acc[4][2] = {};
  pipe_gemm<true, 20>(e, Wih, EMBD, hprev, Whh, HIDN, lds, m0, n0, w, lane, acc);

#pragma unroll
  for (int mi = 0; mi < 4; ++mi) {
    int rowb = m0 + wr * 64 + mi * 16 + lk * 4;
#pragma unroll
    for (int ni = 0; ni < 2; ++ni) {
      int col = n0 + wc * 32 + ni * 16 + lr;
      float bs = bias[col];
#pragma unroll
      for (int j = 0; j < 4; ++j)
        hnew[(size_t)(rowb + j) * HIDN + col] = (bf16)fast_tanh(acc[mi][ni][j] + bs);
    }
  }
}

// ---------------- k2: logits = h@Wout^T + b_out -> fp16 scratch ----------------

__global__ __launch_bounds__(256, 2)
void logits_kernel(const bf16* __restrict__ h,    // [N][HIDN]
                   const bf16* __restrict__ Wout, // [VOC][HIDN]
                   const float* __restrict__ bout,
                   h16* __restrict__ lbuf)        // [N][VOC]
{
  __shared__ bf16 lds[3 * 12288];
  const int tid = threadIdx.x;
  const int lane = tid & 63;
  const int w = tid >> 6;
  const int wr = w >> 1, wc = w & 1;
  const int id = (blockIdx.x & 7) * 64 + (blockIdx.x >> 3);
  const int m0 = (id >> 4) * 128;
  const int n0 = (id & 15) * 64;
  const int lr = lane & 15, lk = lane >> 4;

  f32x4 acc[4][2] = {};
  pipe_gemm<false, 16>(h, Wout, HIDN, nullptr, nullptr, 0, lds, m0, n0, w, lane, acc);

#pragma unroll
  for (int mi = 0; mi < 4; ++mi) {
    int rowb = m0 + wr * 64 + mi * 16 + lk * 4;
#pragma unroll
    for (int ni = 0; ni < 2; ++ni) {
      int col = n0 + wc * 32 + ni * 16 + lr;
      float bs = bout[col];
#pragma unroll
      for (int j = 0; j < 4; ++j) {
        int row = rowb + j;
        lbuf[(size_t)row * VOC + col] = (h16)(acc[mi][ni][j] + bs);
      }
    }
  }
}

// ---------------- k3: softmax((l+g)) -> fp32 d_out + e_next = x@Wemb^T + b_emb ----------
// 1024 threads (16 waves): 1 row/wave softmax, 16 cols/wave emb GEMM.

__global__ __launch_bounds__(1024)
void softmax_emb_kernel(const h16* __restrict__ lbuf,  // [N][VOC]
                        const float* __restrict__ gum, // [N][VOC] (step slice)
                        const bf16* __restrict__ Wemb, // [EMBD][VOC]
                        const float* __restrict__ bemb,
                        float* __restrict__ out,       // [N][NSTEP][VOC]
                        bf16* __restrict__ enext,      // [N][EMBD]
                        int step)
{
  __shared__ bf16 xs[16 * 1032];
  const int tid = threadIdx.x;
  const int lane = tid & 63;
  const int w = tid >> 6;       // 0..15
  const int n0 = blockIdx.x * 16;

  // --- softmax: wave w handles row w ---
  {
    int r = w;
    const h16* lrow = lbuf + (size_t)(n0 + r) * VOC;
    const float* grow = gum + (size_t)(n0 + r) * VOC;
    float s[16];
    float m = -1e30f;
#pragma unroll
    for (int i = 0; i < 2; ++i) {
      h16x8 lv = *(const h16x8*)&lrow[i * 512 + lane * 8];
      f32x4 g0 = *(const f32x4*)&grow[i * 512 + lane * 8];
      f32x4 g1 = *(const f32x4*)&grow[i * 512 + lane * 8 + 4];
#pragma unroll
      for (int j = 0; j < 4; ++j) {
        float f0 = (float)lv[j] + g0[j];
        float f1 = (float)lv[4 + j] + g1[j];
        s[i * 8 + j] = f0; s[i * 8 + 4 + j] = f1;
        m = fmaxf(m, fmaxf(f0, f1));
      }
    }
#pragma unroll
    for (int off = 32; off; off >>= 1) m = fmaxf(m, __shfl_xor(m, off));
    float sum = 0.f;
#pragma unroll
    for (int i = 0; i < 16; ++i) { s[i] = __expf(s[i] - m); sum += s[i]; }
#pragma unroll
    for (int off = 32; off; off >>= 1) sum += __shfl_xor(sum, off);
    float inv = 1.0f / sum;
    float* orow = out + ((size_t)(n0 + r) * NSTEP + step) * VOC;
#pragma unroll
    for (int i = 0; i < 2; ++i) {
      f32x4 v0, v1;
      bf16x8 bv;
#pragma unroll
      for (int j = 0; j < 4; ++j) {
        float x0 = s[i * 8 + j] * inv;
        float x1 = s[i * 8 + 4 + j] * inv;
        v0[j] = x0; v1[j] = x1;
        bv[j] = (bf16)x0; bv[4 + j] = (bf16)x1;
      }
      *(f32x4*)&orow[i * 512 + lane * 8] = v0;
      *(f32x4*)&orow[i * 512 + lane * 8 + 4] = v1;
      *(bf16x8*)&xs[r * 1032 + i * 512 + lane * 8] = bv;
    }
  }
  __syncthreads();

  // --- emb GEMM: wave w computes cols [w*16, w*16+16) over 16 rows ---
  const int lr = lane & 15, lk = lane >> 4;
  f32x4 acc = {};
  const int col = w * 16 + lr;
  for (int k0 = 0; k0 < VOC; k0 += 32) {
    bf16x8 a = *(bf16x8*)&xs[lr * 1032 + k0 + lk * 8];
    bf16x8 b = *(const bf16x8*)&Wemb[(size_t)col * VOC + k0 + lk * 8];
    acc = mfma16(a, b, acc);
  }
  float bb = bemb[col];
#pragma unroll
  for (int j = 0; j < 4; ++j) {
    int n = n0 + lk * 4 + j;
    enext[(size_t)n * EMBD + col] = (bf16)(acc[j] + bb);
  }
}

// ---------------- launch ----------------

extern "C" void kernel_launch(void* const* d_in, const int* in_sizes, int n_in,
                              void* d_out, int out_size, void* d_ws, size_t ws_size,
                              hipStream_t stream) {
  const float* target  = (const float*)d_in[0];
  const float* gumbels = (const float*)d_in[1];
  const float* sos     = (const float*)d_in[2];
  const float* W_ih    = (const float*)d_in[3];
  const float* b_ih    = (const float*)d_in[4];
  const float* W_hh    = (const float*)d_in[5];
  const float* b_hh    = (const float*)d_in[6];
  const float* W_out   = (const float*)d_in[7];
  const float* b_out   = (const float*)d_in[8];
  const float* W_emb   = (const float*)d_in[9];
  const float* b_emb   = (const float*)d_in[10];
  float* out = (float*)d_out;

  char* ws = (char*)d_ws;
  bf16* wih_b  = (bf16*)(ws);                // 512 KB
  bf16* whh_b  = (bf16*)(ws + (1u << 20));   // 2 MB
  bf16* wout_b = (bf16*)(ws + (3u << 20));   // 2 MB
  bf16* wemb_b = (bf16*)(ws + (5u << 20));   // 512 KB
  float* bias1 = (float*)(ws + (6u << 20));  // 4 KB
  bf16* hbuf0  = (bf16*)(ws + (7u << 20));   // 8 MB
  bf16* hbuf1  = (bf16*)(ws + (15u << 20));  // 8 MB
  bf16* ebuf   = (bf16*)(ws + (23u << 20));  // 2 MB
  h16*  lbuf   = (h16*) (ws + (25u << 20));  // 8 MB

  prep_kernel<<<2048, 256, 0, stream>>>(W_ih, W_hh, W_out, W_emb, target, sos,
                                        b_ih, b_hh, wih_b, whh_b, wout_b, wemb_b,
                                        hbuf0, ebuf, bias1);

  bf16* hb[2] = {hbuf0, hbuf1};
  for (int t = 0; t < NSTEP; ++t) {
    bf16* hp = hb[t & 1];
    bf16* hn = hb[(t + 1) & 1];
    rnn_cell_kernel<<<(N_TOT / 128) * (HIDN / 64), 256, 0, stream>>>(
        ebuf, hp, wih_b, whh_b, bias1, hn);
    logits_kernel<<<(N_TOT / 128) * (VOC / 64), 256, 0, stream>>>(
        hn, wout_b, b_out, lbuf);
    softmax_emb_kernel<<<N_TOT / 16, 1024, 0, stream>>>(
        lbuf, gumbels + (size_t)t * N_TOT * VOC, wemb_b, b_emb, out, ebuf, t);
  }
}